// Round 1
// baseline (797.469 us; speedup 1.0000x reference)
//
#include <hip/hip_runtime.h>
#include <math.h>

#define DD 4096
#define EE 64
#define NTOK 8192

// ---------------------------------------------------------------------------
// prep: widen W and b to f64 in workspace (exact converts)
// ---------------------------------------------------------------------------
__global__ void moirai_prep(const float* __restrict__ W, const float* __restrict__ b,
                            double* __restrict__ w64, double* __restrict__ b64) {
    int i = blockIdx.x * 256 + threadIdx.x;
    if (i < EE * DD) w64[i] = (double)W[i];
    if (i < EE)      b64[i] = (double)b[i];
}

// ---------------------------------------------------------------------------
// gemm: lane = token. Each wave: 64 tokens x 64 experts x (D/KS) k's, f64 acc.
// x streamed per-lane via float4 with one-quad prefetch; W via uniform
// (scalar-path) f64 loads. Partials to ws: part[ks][token][e] f64.
// ---------------------------------------------------------------------------
__global__ __launch_bounds__(256, 1) void moirai_gemm(
        const float* __restrict__ x, const double* __restrict__ w64,
        double* __restrict__ part, int kslen) {
    const int token = (blockIdx.x & 31) * 256 + threadIdx.x;  // 32 token-blocks
    const int ks    = blockIdx.x >> 5;

    const float* xrow = x + (size_t)token * DD + (size_t)ks * kslen;

    double acc[EE];
#pragma unroll
    for (int e = 0; e < EE; e++) acc[e] = 0.0;

    const int nkq = kslen >> 2;
    const double* wbase = w64 + (size_t)ks * kslen;

    float4 cur = *(const float4*)(xrow);
    for (int kq = 0; kq < nkq - 1; kq++) {
        float4 nxt = *(const float4*)(xrow + (size_t)(kq + 1) * 4);
        const double x0 = (double)cur.x, x1 = (double)cur.y;
        const double x2 = (double)cur.z, x3 = (double)cur.w;
        const double* wp = wbase + (size_t)kq * 4;
#pragma unroll
        for (int e = 0; e < EE; e++) {
            const double* we = wp + (size_t)e * DD;
            acc[e] += x0 * we[0] + x1 * we[1] + x2 * we[2] + x3 * we[3];
        }
        cur = nxt;
    }
    {   // peeled last iteration (no prefetch -> no OOB read)
        const double x0 = (double)cur.x, x1 = (double)cur.y;
        const double x2 = (double)cur.z, x3 = (double)cur.w;
        const double* wp = wbase + (size_t)(nkq - 1) * 4;
#pragma unroll
        for (int e = 0; e < EE; e++) {
            const double* we = wp + (size_t)e * DD;
            acc[e] += x0 * we[0] + x1 * we[1] + x2 * we[2] + x3 * we[3];
        }
    }

    double* po = part + ((size_t)ks * NTOK + token) * EE;
#pragma unroll
    for (int e = 0; e < EE; e++) po[e] = acc[e];
}

// ---------------------------------------------------------------------------
// topk: one wave per token. lane = expert. Sum KS partials + bias (f64),
// butterfly top-2 with jax tie-breaking (lower index first), softmax(2).
// Output layout: [gate_probs 16384 f32][indices-as-f32 16384].
// ---------------------------------------------------------------------------
__global__ void moirai_topk(const double* __restrict__ part,
                            const double* __restrict__ b64,
                            float* __restrict__ out, int KS) {
    const int lane  = threadIdx.x & 63;
    const int token = blockIdx.x * 4 + (threadIdx.x >> 6);

    double v = b64[lane];
    for (int ks = 0; ks < KS; ks++)
        v += part[((size_t)ks * NTOK + token) * EE + lane];

    double v1 = v, v2 = -1.0e300;
    int    i1 = lane, i2 = 127;

#pragma unroll
    for (int off = 1; off < 64; off <<= 1) {
        double u1 = __shfl_xor(v1, off);
        double u2 = __shfl_xor(v2, off);
        int    j1 = __shfl_xor(i1, off);
        int    j2 = __shfl_xor(i2, off);
        bool u1_beats_v1 = (u1 > v1) || (u1 == v1 && j1 < i1);
        if (u1_beats_v1) {
            bool v1_beats_u2 = (v1 > u2) || (v1 == u2 && i1 < j2);
            if (v1_beats_u2) { v2 = v1; i2 = i1; }
            else             { v2 = u2; i2 = j2; }
            v1 = u1; i1 = j1;
        } else {
            bool u1_beats_v2 = (u1 > v2) || (u1 == v2 && j1 < i2);
            if (u1_beats_v2) { v2 = u1; i2 = j1; }
        }
    }

    if (lane == 0) {
        double e2 = exp(v2 - v1);     // v1 >= v2, so e2 <= 1 (stable)
        double s  = 1.0 + e2;
        out[token * 2 + 0] = (float)(1.0 / s);
        out[token * 2 + 1] = (float)(e2 / s);
        out[NTOK * 2 + token * 2 + 0] = (float)i1;
        out[NTOK * 2 + token * 2 + 1] = (float)i2;
    }
}

// ---------------------------------------------------------------------------
extern "C" void kernel_launch(void* const* d_in, const int* in_sizes, int n_in,
                              void* d_out, int out_size, void* d_ws, size_t ws_size,
                              hipStream_t stream) {
    const float* x = (const float*)d_in[0];
    const float* W = (const float*)d_in[1];
    const float* b = (const float*)d_in[2];
    float* out = (float*)d_out;

    // workspace layout: [w64: 2 MB][b64: 512 B, padded to 4 KB][partials]
    double* w64  = (double*)d_ws;
    double* b64  = (double*)((char*)d_ws + (size_t)EE * DD * 8);
    double* part = (double*)((char*)d_ws + (size_t)EE * DD * 8 + 4096);

    int KS = 16;  // K-split factor; shrink if workspace is small
    while (KS > 1) {
        size_t need = (size_t)EE * DD * 8 + 4096 + (size_t)KS * NTOK * EE * 8;
        if (need <= ws_size) break;
        KS >>= 1;
    }
    const int kslen = DD / KS;

    moirai_prep<<<(EE * DD + 255) / 256, 256, 0, stream>>>(W, b, w64, b64);
    moirai_gemm<<<32 * KS, 256, 0, stream>>>(x, w64, part, kslen);
    moirai_topk<<<NTOK / 4, 256, 0, stream>>>(part, b64, out, KS);
}

// Round 2
// 142.843 us; speedup vs baseline: 5.5828x; 5.5828x over previous
//
#include <hip/hip_runtime.h>
#include <math.h>

#define DD 4096
#define EE 64
#define NTOK 8192
#define BM 128          // tokens per block
#define KC 32           // K-chunk staged in LDS
#define NMB (NTOK / BM) // 64 token-blocks

// ---------------------------------------------------------------------------
// gemm: 256 threads, each computes a 4-token x 8-expert f64 tile.
// x,W staged in LDS as f32 (half the LDS bytes), converted to f64 at read.
// Per k: 1 ds_read_b128 (x) + 2 ds_read_b128 (w) + 12 cvt + 32 f64 FMA.
// Partials (f64, exact) to ws: part[ks][token][e].
// ---------------------------------------------------------------------------
__global__ __launch_bounds__(256, 2) void moirai_gemm(
        const float* __restrict__ x, const float* __restrict__ W,
        double* __restrict__ part, int kslen) {
    __shared__ float xs[KC][BM];   // 16 KB
    __shared__ float wsh[KC][EE];  //  8 KB

    const int t    = threadIdx.x;
    const int tx   = t & 7;        // expert group: e = tx*8 + ee
    const int ty   = t >> 3;       // token group:  m = ty*4 + mm (ty 0..31)
    const int mblk = blockIdx.x & (NMB - 1);
    const int ks   = blockIdx.x >> 6;   // grid = NMB * KS
    const int m0   = mblk * BM;
    const int k0   = ks * kslen;

    double acc[4][8];
#pragma unroll
    for (int mm = 0; mm < 4; mm++)
#pragma unroll
        for (int ee = 0; ee < 8; ee++) acc[mm][ee] = 0.0;

    for (int c = 0; c < kslen; c += KC) {
        __syncthreads();
        // stage x: 128 rows x 32 f32 = 1024 float4, 4 per thread (coalesced
        // 128B segments), scattered transposed into xs[k][m]
#pragma unroll
        for (int i = 0; i < 4; i++) {
            int idx = t + i * 256;
            int r   = idx >> 3;     // token row 0..127
            int sg  = idx & 7;      // 16B segment 0..7
            float4 v = *(const float4*)(x + (size_t)(m0 + r) * DD + (k0 + c + sg * 4));
            xs[sg * 4 + 0][r] = v.x;
            xs[sg * 4 + 1][r] = v.y;
            xs[sg * 4 + 2][r] = v.z;
            xs[sg * 4 + 3][r] = v.w;
        }
        // stage w: 64 rows x 32 f32 = 512 float4, 2 per thread
#pragma unroll
        for (int i = 0; i < 2; i++) {
            int idx = t + i * 256;
            int e   = idx >> 3;     // expert row 0..63
            int sg  = idx & 7;
            float4 v = *(const float4*)(W + (size_t)e * DD + (k0 + c + sg * 4));
            wsh[sg * 4 + 0][e] = v.x;
            wsh[sg * 4 + 1][e] = v.y;
            wsh[sg * 4 + 2][e] = v.z;
            wsh[sg * 4 + 3][e] = v.w;
        }
        __syncthreads();

#pragma unroll 4
        for (int k = 0; k < KC; k++) {
            float4 xa = *(const float4*)&xs[k][ty * 4];      // conflict-free
            float4 wa = *(const float4*)&wsh[k][tx * 8];     // 2-way (free)
            float4 wb = *(const float4*)&wsh[k][tx * 8 + 4];
            double xv[4] = {(double)xa.x, (double)xa.y, (double)xa.z, (double)xa.w};
            double wv[8] = {(double)wa.x, (double)wa.y, (double)wa.z, (double)wa.w,
                            (double)wb.x, (double)wb.y, (double)wb.z, (double)wb.w};
#pragma unroll
            for (int mm = 0; mm < 4; mm++)
#pragma unroll
                for (int ee = 0; ee < 8; ee++)
                    acc[mm][ee] += xv[mm] * wv[ee];
        }
    }

    // write partials: 64B contiguous per thread-row -> b128 stores
#pragma unroll
    for (int mm = 0; mm < 4; mm++) {
        double* po = part + ((size_t)ks * NTOK + (m0 + ty * 4 + mm)) * EE + tx * 8;
#pragma unroll
        for (int ee = 0; ee < 8; ee++) po[ee] = acc[mm][ee];
    }
}

// ---------------------------------------------------------------------------
// topk: one wave per token. lane = expert. Sum KS partials + bias (f64),
// butterfly top-2 with jax tie-breaking (lower index first), softmax(2).
// Output layout: [gate_probs 16384 f32][indices-as-f32 16384].
// ---------------------------------------------------------------------------
__global__ void moirai_topk(const double* __restrict__ part,
                            const float* __restrict__ b,
                            float* __restrict__ out, int KS) {
    const int lane  = threadIdx.x & 63;
    const int token = blockIdx.x * 4 + (threadIdx.x >> 6);

    double v = (double)b[lane];
    for (int ks = 0; ks < KS; ks++)
        v += part[((size_t)ks * NTOK + token) * EE + lane];

    double v1 = v, v2 = -1.0e300;
    int    i1 = lane, i2 = 127;

#pragma unroll
    for (int off = 1; off < 64; off <<= 1) {
        double u1 = __shfl_xor(v1, off);
        double u2 = __shfl_xor(v2, off);
        int    j1 = __shfl_xor(i1, off);
        int    j2 = __shfl_xor(i2, off);
        bool u1_beats_v1 = (u1 > v1) || (u1 == v1 && j1 < i1);
        if (u1_beats_v1) {
            bool v1_beats_u2 = (v1 > u2) || (v1 == u2 && i1 < j2);
            if (v1_beats_u2) { v2 = v1; i2 = i1; }
            else             { v2 = u2; i2 = j2; }
            v1 = u1; i1 = j1;
        } else {
            bool u1_beats_v2 = (u1 > v2) || (u1 == v2 && j1 < i2);
            if (u1_beats_v2) { v2 = u1; i2 = j1; }
        }
    }

    if (lane == 0) {
        double e2 = exp(v2 - v1);     // v1 >= v2 -> stable
        double s  = 1.0 + e2;
        out[token * 2 + 0] = (float)(1.0 / s);
        out[token * 2 + 1] = (float)(e2 / s);
        out[NTOK * 2 + token * 2 + 0] = (float)i1;
        out[NTOK * 2 + token * 2 + 1] = (float)i2;
    }
}

// ---------------------------------------------------------------------------
extern "C" void kernel_launch(void* const* d_in, const int* in_sizes, int n_in,
                              void* d_out, int out_size, void* d_ws, size_t ws_size,
                              hipStream_t stream) {
    const float* x = (const float*)d_in[0];
    const float* W = (const float*)d_in[1];
    const float* b = (const float*)d_in[2];
    float* out = (float*)d_out;

    double* part = (double*)d_ws;

    int KS = 8;  // K-split; kslen must stay a multiple of KC
    while (KS > 1) {
        size_t need = (size_t)KS * NTOK * EE * 8;
        if (need <= ws_size) break;
        KS >>= 1;
    }
    const int kslen = DD / KS;

    moirai_gemm<<<NMB * KS, 256, 0, stream>>>(x, W, part, kslen);
    moirai_topk<<<NTOK / 4, 256, 0, stream>>>(part, b, out, KS);
}